// Round 2
// baseline (429.866 us; speedup 1.0000x reference)
//
#include <hip/hip_runtime.h>
#include <hip/hip_bf16.h>
#include <cstdint>

#define N_NODES 50000
#define N_EDGES 1600000
#define DIM 128
#define NREL 8
#define LN_EPS 1e-5f

#define NKEYS (N_NODES * NREL)          // 400000
#define SCAN_CHUNK 1024                 // keys per scan block (256 thr x 4)
#define SCAN_NBLK ((NKEYS + SCAN_CHUNK - 1) / SCAN_CHUNK)  // 391

#define A_STRIDE 136                    // ushorts per LDS A row (128 + 8 pad)

#define XB_BLOCKS 6250                  // N_NODES*DIM/4 / 256
#define BT_BLOCKS 576                   // 9*128*128 / 256

typedef unsigned short ushort_t;
typedef short short8 __attribute__((ext_vector_type(8)));
typedef float f32x4 __attribute__((ext_vector_type(4)));
typedef unsigned uintx4 __attribute__((ext_vector_type(4)));

__device__ inline ushort_t f2bf(float f) {
    union { float f; unsigned u; } v; v.f = f;
    unsigned r = (v.u + 0x7FFFu + ((v.u >> 16) & 1u)) >> 16;
    return (ushort_t)r;
}
__device__ inline float bf_lo(unsigned u) {
    union { unsigned u; float f; } v; v.u = u << 16;
    return v.f;
}
__device__ inline float bf_hi(unsigned u) {
    union { unsigned u; float f; } v; v.u = u & 0xffff0000u;
    return v.f;
}

// ---------------------------------------------------------------------------
// Fused prep: xb (x fp32 -> bf16), Bt (W transposed bf16), and one zero row
// appended at xb[N_NODES] (gather padding target), one launch.
// ---------------------------------------------------------------------------
__global__ __launch_bounds__(256) void prep_kernel(const float* __restrict__ x,
                                                   ushort_t* __restrict__ xb,
                                                   const float* __restrict__ W_rel,
                                                   const float* __restrict__ W_root,
                                                   ushort_t* __restrict__ Bt) {
    int b = blockIdx.x;
    if (b < XB_BLOCKS) {
        int i = b * 256 + threadIdx.x;            // float4 index
        float4 v = ((const float4*)x)[i];
        unsigned lo = (unsigned)f2bf(v.x) | ((unsigned)f2bf(v.y) << 16);
        unsigned hi = (unsigned)f2bf(v.z) | ((unsigned)f2bf(v.w) << 16);
        ((uint2*)xb)[i] = make_uint2(lo, hi);
    } else if (b < XB_BLOCKS + BT_BLOCKS) {
        int i = (b - XB_BLOCKS) * 256 + threadIdx.x;
        int r   = i >> 14;
        int rem = i & 16383;
        int n   = rem >> 7;
        int k   = rem & 127;
        const float* W = (r < NREL) ? (W_rel + (size_t)r * DIM * DIM) : W_root;
        Bt[i] = f2bf(W[(size_t)k * DIM + n]);
    } else {
        // zero row at node index N_NODES: 128 bf16 = 32 x uint2
        if (threadIdx.x < 32)
            ((uint2*)(xb + (size_t)N_NODES * DIM))[threadIdx.x] = make_uint2(0u, 0u);
    }
}

// ---------------------------------------------------------------------------
// Count edges per key AND record each edge's within-bucket rank, packed as
// (key << 13) | rank.
// ---------------------------------------------------------------------------
__global__ __launch_bounds__(256) void count_rank_kernel(const int* __restrict__ ei,
                                                         const int* __restrict__ et,
                                                         unsigned* __restrict__ cnt,
                                                         unsigned* __restrict__ krk) {
    int e = blockIdx.x * 256 + threadIdx.x;
    if (e < N_EDGES) {
        int dst = ei[N_EDGES + e];
        unsigned key = (unsigned)dst * NREL + (unsigned)et[e];
        unsigned rank = atomicAdd(&cnt[key], 1u);
        krk[e] = (key << 13) | rank;
    }
}

// ---------------------------------------------------------------------------
// Block-local exclusive scan: meta[key] = (local_excl_offset, cnt), plus
// per-block sums. Consumers add bsums[key>>10] for the global offset.
// ---------------------------------------------------------------------------
__global__ __launch_bounds__(256) void scan1_kernel(const unsigned* __restrict__ cnt,
                                                    uint2* __restrict__ meta,
                                                    unsigned* __restrict__ bsums) {
    __shared__ unsigned lds[256];
    int tid = threadIdx.x;
    int i0  = blockIdx.x * SCAN_CHUNK + tid * 4;
    unsigned v[4], incl[4];
    unsigned s = 0;
#pragma unroll
    for (int j = 0; j < 4; ++j) {
        v[j] = (i0 + j < NKEYS) ? cnt[i0 + j] : 0u;
        s += v[j];
        incl[j] = s;
    }
    lds[tid] = s;
    __syncthreads();
    for (int off = 1; off < 256; off <<= 1) {
        unsigned a = (tid >= off) ? lds[tid - off] : 0u;
        __syncthreads();
        lds[tid] += a;
        __syncthreads();
    }
    unsigned base = lds[tid] - s;
#pragma unroll
    for (int j = 0; j < 4; ++j) {
        if (i0 + j < NKEYS) meta[i0 + j] = make_uint2(base + incl[j] - v[j], v[j]);
    }
    if (tid == 255) bsums[blockIdx.x] = lds[255];
}

__global__ __launch_bounds__(512) void scan2_kernel(unsigned* __restrict__ bsums) {
    __shared__ unsigned lds[512];
    int tid = threadIdx.x;
    unsigned v = (tid < SCAN_NBLK) ? bsums[tid] : 0u;
    lds[tid] = v;
    __syncthreads();
    for (int off = 1; off < 512; off <<= 1) {
        unsigned a = (tid >= off) ? lds[tid - off] : 0u;
        __syncthreads();
        lds[tid] += a;
        __syncthreads();
    }
    if (tid < SCAN_NBLK) bsums[tid] = lds[tid] - v;
}

// ---------------------------------------------------------------------------
// Atomic-free counting-sort fill: p = meta[key].x + bsums[key>>10] + rank.
// ---------------------------------------------------------------------------
__global__ __launch_bounds__(256) void fill_kernel(const int* __restrict__ ei,
                                                   const unsigned* __restrict__ krk,
                                                   const uint2* __restrict__ meta,
                                                   const unsigned* __restrict__ bsums,
                                                   int* __restrict__ sorted_src) {
    int e = blockIdx.x * 256 + threadIdx.x;
    if (e < N_EDGES) {
        unsigned kr   = krk[e];
        unsigned key  = kr >> 13;
        unsigned rank = kr & 8191u;
        unsigned p = meta[key].x + bsums[key >> 10] + rank;
        sorted_src[p] = ei[e];
    }
}

// ---------------------------------------------------------------------------
// R13: each half-wave owns TWO adjacent buckets with independent accumulator
// sets -> 2 independent load chains in flight per half-wave (the kernel was
// latency-bound at VALUBusy 49% with one chain). Zero-row padding (index
// N_NODES) lets the fused inner loop run to max(rem0,rem1) unconditionally;
// the shorter bucket's surplus gathers hit the L1-hot zero row.
// ---------------------------------------------------------------------------
__global__ __launch_bounds__(256) void aggregate_kernel(const uint2* __restrict__ meta,
                                                        const unsigned* __restrict__ bsums,
                                                        const int* __restrict__ sorted_src,
                                                        const ushort_t* __restrict__ xb,
                                                        ushort_t* __restrict__ h,
                                                        int r0, int cr) {
    int hw = threadIdx.x >> 5;                      // half-wave id 0..7
    int sl = threadIdx.x & 31;                      // lane covers 4 feats
    int g0 = blockIdx.x * 16 + hw * 2;              // first bucket
    int g1 = g0 + 1;
    int total = N_NODES * cr;
    if (g0 >= total) return;

    unsigned key0, key1;
    if (cr == NREL) {
        key0 = (unsigned)g0;
        key1 = (unsigned)g1;
    } else {
        int n0 = g0 / cr, rl0 = g0 - n0 * cr;
        key0 = (unsigned)n0 * NREL + (unsigned)(r0 + rl0);
        int n1 = g1 / cr, rl1 = g1 - n1 * cr;
        key1 = (unsigned)n1 * NREL + (unsigned)(r0 + rl1);
    }
    uint2 md0 = meta[key0];
    unsigned st0 = md0.x + bsums[key0 >> 10];
    unsigned mc0 = md0.y;
    unsigned st1 = 0u, mc1 = 0u;
    if (g1 < total) {
        uint2 md1 = meta[key1];
        st1 = md1.x + bsums[key1 >> 10];
        mc1 = md1.y;
    }

    float a00 = 0.f, a01 = 0.f, a02 = 0.f, a03 = 0.f;
    float a10 = 0.f, a11 = 0.f, a12 = 0.f, a13 = 0.f;
    const char* xbase = (const char*)xb;
    unsigned slb = (unsigned)sl << 3;               // byte offset within row

    unsigned c0 = 0, c1 = 0;
    while (c0 < mc0 || c1 < mc1) {
        // two independent coalesced index loads (OOR lanes -> zero row)
        int sv0 = (c0 + (unsigned)sl < mc0) ? sorted_src[st0 + c0 + sl] : N_NODES;
        int sv1 = (c1 + (unsigned)sl < mc1) ? sorted_src[st1 + c1 + sl] : N_NODES;
        unsigned rem0 = (c0 < mc0) ? ((mc0 - c0 > 32u) ? 32u : (mc0 - c0)) : 0u;
        unsigned rem1 = (c1 < mc1) ? ((mc1 - c1 > 32u) ? 32u : (mc1 - c1)) : 0u;
        unsigned rm = rem0 > rem1 ? rem0 : rem1;
        for (unsigned j = 0; j < rm; j += 4) {
            int s00 = __shfl(sv0, (int)j,     32);
            int s01 = __shfl(sv0, (int)j + 1, 32);
            int s02 = __shfl(sv0, (int)j + 2, 32);
            int s03 = __shfl(sv0, (int)j + 3, 32);
            int s10 = __shfl(sv1, (int)j,     32);
            int s11 = __shfl(sv1, (int)j + 1, 32);
            int s12 = __shfl(sv1, (int)j + 2, 32);
            int s13 = __shfl(sv1, (int)j + 3, 32);
            uint2 d00 = *(const uint2*)(xbase + ((((unsigned)s00) << 8) | slb));
            uint2 d01 = *(const uint2*)(xbase + ((((unsigned)s01) << 8) | slb));
            uint2 d02 = *(const uint2*)(xbase + ((((unsigned)s02) << 8) | slb));
            uint2 d03 = *(const uint2*)(xbase + ((((unsigned)s03) << 8) | slb));
            uint2 d10 = *(const uint2*)(xbase + ((((unsigned)s10) << 8) | slb));
            uint2 d11 = *(const uint2*)(xbase + ((((unsigned)s11) << 8) | slb));
            uint2 d12 = *(const uint2*)(xbase + ((((unsigned)s12) << 8) | slb));
            uint2 d13 = *(const uint2*)(xbase + ((((unsigned)s13) << 8) | slb));
            a00 += (bf_lo(d00.x) + bf_lo(d01.x)) + (bf_lo(d02.x) + bf_lo(d03.x));
            a01 += (bf_hi(d00.x) + bf_hi(d01.x)) + (bf_hi(d02.x) + bf_hi(d03.x));
            a02 += (bf_lo(d00.y) + bf_lo(d01.y)) + (bf_lo(d02.y) + bf_lo(d03.y));
            a03 += (bf_hi(d00.y) + bf_hi(d01.y)) + (bf_hi(d02.y) + bf_hi(d03.y));
            a10 += (bf_lo(d10.x) + bf_lo(d11.x)) + (bf_lo(d12.x) + bf_lo(d13.x));
            a11 += (bf_hi(d10.x) + bf_hi(d11.x)) + (bf_hi(d12.x) + bf_hi(d13.x));
            a12 += (bf_lo(d10.y) + bf_lo(d11.y)) + (bf_lo(d12.y) + bf_lo(d13.y));
            a13 += (bf_hi(d10.y) + bf_hi(d11.y)) + (bf_hi(d12.y) + bf_hi(d13.y));
        }
        c0 += rem0;
        c1 += rem1;
    }

    float inv0 = 1.0f / fmaxf((float)mc0, 1.0f);
    unsigned lo0 = (unsigned)f2bf(a00 * inv0) | ((unsigned)f2bf(a01 * inv0) << 16);
    unsigned hi0 = (unsigned)f2bf(a02 * inv0) | ((unsigned)f2bf(a03 * inv0) << 16);
    ((uint2*)(h + (size_t)g0 * DIM))[sl] = make_uint2(lo0, hi0);
    if (g1 < total) {
        float inv1 = 1.0f / fmaxf((float)mc1, 1.0f);
        unsigned lo1 = (unsigned)f2bf(a10 * inv1) | ((unsigned)f2bf(a11 * inv1) << 16);
        unsigned hi1 = (unsigned)f2bf(a12 * inv1) | ((unsigned)f2bf(a13 * inv1) << 16);
        ((uint2*)(h + (size_t)g1 * DIM))[sl] = make_uint2(lo1, hi1);
    }
}

// ---------------------------------------------------------------------------
// LDS-staged MFMA GEMM + optional fused bias+LN+ReLU.
// R13: B is one 32KB matrix per rel shared by ALL blocks -> L2-broadcast;
// read B fragments directly from global instead of staging to LDS. LDS drops
// 69.6 -> 34.8 KB and __launch_bounds__(512,6) targets 3 blocks/CU (24
// waves, 75% occupancy vs 50%) to hide the A-staging latency.
// ---------------------------------------------------------------------------
__global__ __launch_bounds__(512, 6) void gemm_ln_kernel(const ushort_t* __restrict__ h,
                                                      int cr, int r0,
                                                      const ushort_t* __restrict__ xb,
                                                      const ushort_t* __restrict__ Bt,
                                                      int include_root,
                                                      const float* __restrict__ bias,
                                                      const float* __restrict__ gamma,
                                                      const float* __restrict__ beta,
                                                      float* __restrict__ out,
                                                      int accumulate, int do_ln) {
    __shared__ __align__(16) ushort_t As[128 * A_STRIDE];   // 34.8 KB

    int tid  = threadIdx.x;
    int w    = tid >> 6;          // 0..7
    int lane = tid & 63;
    int m    = lane & 15;
    int quad = lane >> 4;
    int n0   = blockIdx.x * 128;

    f32x4 acc[8];
#pragma unroll
    for (int j = 0; j < 8; ++j) acc[j] = (f32x4){0.f, 0.f, 0.f, 0.f};

    int nrel = cr + include_root;
    for (int rr = 0; rr < nrel; ++rr) {
        int rel = (rr < cr) ? (r0 + rr) : NREL;

        // ---- stage A: 2048 x 16B chunks (128 rows), 4 per thread ----
#pragma unroll
        for (int p = 0; p < 4; ++p) {
            int c = tid + 512 * p;
            int row = c >> 4, ch = c & 15;
            uintx4 v = (uintx4){0u, 0u, 0u, 0u};
            int node = n0 + row;
            if (node < N_NODES) {
                const ushort_t* src = (rr < cr)
                    ? (h + ((size_t)node * cr + rr) * DIM)
                    : (xb + (size_t)node * DIM);
                v = *(const uintx4*)(src + ch * 8);
            }
            *(uintx4*)&As[row * A_STRIDE + ch * 8] = v;
        }
        __syncthreads();

        // ---- 32 MFMA per wave; B fragments straight from global (L2-hit) ----
        const ushort_t* Bb = Bt + (size_t)rel * DIM * DIM;
#pragma unroll
        for (int t = 0; t < 4; ++t) {
            short8 af = *(const short8*)&As[(w * 16 + m) * A_STRIDE + t * 32 + quad * 8];
#pragma unroll
            for (int j = 0; j < 8; ++j) {
                short8 bf = *(const short8*)(Bb + (size_t)(j * 16 + m) * DIM + t * 32 + quad * 8);
                acc[j] = __builtin_amdgcn_mfma_f32_16x16x32_bf16(af, bf, acc[j], 0, 0, 0);
            }
        }
        __syncthreads();
    }

    // ---- epilogue ----
    if (do_ln) {
        float bj[8], gj[8], btj[8];
#pragma unroll
        for (int j = 0; j < 8; ++j) {
            bj[j]  = bias[j * 16 + m];
            gj[j]  = gamma[j * 16 + m];
            btj[j] = beta[j * 16 + m];
        }
#pragma unroll
        for (int i = 0; i < 4; ++i) {
            float s = 0.f, sq = 0.f;
#pragma unroll
            for (int j = 0; j < 8; ++j) {
                float v = acc[j][i] + bj[j];
                s  += v;
                sq += v * v;
            }
#pragma unroll
            for (int off = 1; off < 16; off <<= 1) {
                s  += __shfl_xor(s, off, 64);
                sq += __shfl_xor(sq, off, 64);
            }
            float mean = s * (1.0f / DIM);
            float var  = sq * (1.0f / DIM) - mean * mean;
            float rstd = rsqrtf(var + LN_EPS);
            int node = n0 + w * 16 + quad * 4 + i;
            if (node < N_NODES) {
#pragma unroll
                for (int j = 0; j < 8; ++j) {
                    float v = acc[j][i] + bj[j];
                    v = (v - mean) * rstd * gj[j] + btj[j];
                    out[(size_t)node * DIM + j * 16 + m] = fmaxf(v, 0.f);
                }
            }
        }
    } else {
#pragma unroll
        for (int i = 0; i < 4; ++i) {
            int node = n0 + w * 16 + quad * 4 + i;
            if (node < N_NODES) {
#pragma unroll
                for (int j = 0; j < 8; ++j) {
                    size_t o = (size_t)node * DIM + j * 16 + m;
                    float v = acc[j][i];
                    if (accumulate) v += out[o];
                    out[o] = v;
                }
            }
        }
    }
}

// ---------------------------------------------------------------------------
// Standalone bias + LayerNorm + ReLU (fallback for chunked path).
// ---------------------------------------------------------------------------
__global__ __launch_bounds__(256) void ln_kernel(float* __restrict__ out,
                                                 const float* __restrict__ bias,
                                                 const float* __restrict__ gamma,
                                                 const float* __restrict__ beta) {
    int row  = blockIdx.x * 4 + (threadIdx.x >> 6);
    int lane = threadIdx.x & 63;
    if (row >= N_NODES) return;
    float2 v = *(float2*)(out + (size_t)row * DIM + lane * 2);
    float2 bi = *(const float2*)(bias + lane * 2);
    v.x += bi.x;
    v.y += bi.y;
    float s  = v.x + v.y;
    float sq = v.x * v.x + v.y * v.y;
#pragma unroll
    for (int off = 32; off > 0; off >>= 1) {
        s  += __shfl_xor(s, off, 64);
        sq += __shfl_xor(sq, off, 64);
    }
    float mean = s * (1.0f / DIM);
    float var  = sq * (1.0f / DIM) - mean * mean;
    float rstd = rsqrtf(var + LN_EPS);
    float2 g = *(const float2*)(gamma + lane * 2);
    float2 b = *(const float2*)(beta + lane * 2);
    v.x = fmaxf((v.x - mean) * rstd * g.x + b.x, 0.f);
    v.y = fmaxf((v.y - mean) * rstd * g.y + b.y, 0.f);
    *(float2*)(out + (size_t)row * DIM + lane * 2) = v;
}

// ---------------------------------------------------------------------------
extern "C" void kernel_launch(void* const* d_in, const int* in_sizes, int n_in,
                              void* d_out, int out_size, void* d_ws, size_t ws_size,
                              hipStream_t stream) {
    const float* x      = (const float*)d_in[0];
    const int*   ei     = (const int*)d_in[1];
    const int*   et     = (const int*)d_in[2];
    const float* W_rel  = (const float*)d_in[4];
    const float* W_root = (const float*)d_in[5];
    const float* bias   = (const float*)d_in[6];
    const float* gamma  = (const float*)d_in[7];
    const float* beta   = (const float*)d_in[8];
    float*       out    = (float*)d_out;

    // ---- workspace layout ----
    char* ws = (char*)d_ws;
    size_t off = 0;
    auto alloc = [&](size_t bytes) { char* p = ws + off; off = (off + bytes + 255) & ~(size_t)255; return p; };
    unsigned* cnt        = (unsigned*)alloc((size_t)NKEYS * 4);
    uint2*    meta       = (uint2*)alloc((size_t)NKEYS * 8);
    unsigned* bsums      = (unsigned*)alloc((size_t)SCAN_NBLK * 4);
    unsigned* krk        = (unsigned*)alloc((size_t)N_EDGES * 4);
    int*      sorted_src = (int*)alloc((size_t)N_EDGES * 4);
    ushort_t* Bt         = (ushort_t*)alloc((size_t)9 * DIM * DIM * 2);
    ushort_t* xb         = (ushort_t*)alloc((size_t)(N_NODES + 1) * DIM * 2);  // +1 zero row
    size_t fixedOff = off;
    ushort_t* h = (ushort_t*)(ws + fixedOff);
    size_t availB = ws_size > fixedOff ? ws_size - fixedOff : 0;
    size_t perRel = (size_t)N_NODES * DIM * 2;   // 12.8 MB per relation (bf16)
    int chunkR = (int)(availB / perRel);
    if (chunkR > NREL) chunkR = NREL;
    if (chunkR < 1)    chunkR = 1;

    // ---- build counting sort (rank recorded during count; no fill atomic) ----
    hipMemsetAsync(cnt, 0, (size_t)NKEYS * 4, stream);
    prep_kernel<<<XB_BLOCKS + BT_BLOCKS + 1, 256, 0, stream>>>(x, xb, W_rel, W_root, Bt);
    count_rank_kernel<<<(N_EDGES + 255) / 256, 256, 0, stream>>>(ei, et, cnt, krk);
    scan1_kernel<<<SCAN_NBLK, 256, 0, stream>>>(cnt, meta, bsums);
    scan2_kernel<<<1, 512, 0, stream>>>(bsums);
    fill_kernel<<<(N_EDGES + 255) / 256, 256, 0, stream>>>(ei, krk, meta, bsums, sorted_src);

    int gemmGrid = (N_NODES + 127) / 128;   // 391 blocks

    if (chunkR >= NREL) {
        int nbuck = N_NODES * NREL;
        aggregate_kernel<<<(nbuck + 15) / 16, 256, 0, stream>>>(meta, bsums, sorted_src,
                                                                xb, h, 0, NREL);
        gemm_ln_kernel<<<gemmGrid, 512, 0, stream>>>(h, NREL, 0, xb, Bt, 1,
                                                     bias, gamma, beta, out, 0, 1);
    } else {
        for (int r0 = 0; r0 < NREL; r0 += chunkR) {
            int cr = (NREL - r0 < chunkR) ? (NREL - r0) : chunkR;
            int nbuck = N_NODES * cr;
            aggregate_kernel<<<(nbuck + 15) / 16, 256, 0, stream>>>(meta, bsums, sorted_src,
                                                                    xb, h, r0, cr);
            int include_root = (r0 + cr == NREL) ? 1 : 0;
            gemm_ln_kernel<<<gemmGrid, 512, 0, stream>>>(h, cr, r0, xb, Bt, include_root,
                                                         bias, gamma, beta, out,
                                                         r0 > 0 ? 1 : 0, 0);
        }
        ln_kernel<<<(N_NODES + 3) / 4, 256, 0, stream>>>(out, bias, gamma, beta);
    }
}

// Round 3
// 314.256 us; speedup vs baseline: 1.3679x; 1.3679x over previous
//
#include <hip/hip_runtime.h>
#include <hip/hip_bf16.h>
#include <cstdint>

#define N_NODES 50000
#define N_EDGES 1600000
#define DIM 128
#define NREL 8
#define LN_EPS 1e-5f

#define NKEYS (N_NODES * NREL)          // 400000
#define SCAN_CHUNK 1024                 // keys per scan block (256 thr x 4)
#define SCAN_NBLK ((NKEYS + SCAN_CHUNK - 1) / SCAN_CHUNK)  // 391

#define A_STRIDE 136                    // ushorts per LDS A row (128 + 8 pad)
#define B_STRIDE 136                    // ushorts per LDS B row

#define XB_BLOCKS 6250                  // N_NODES*DIM/4 / 256
#define BT_BLOCKS 576                   // 9*128*128 / 256

typedef unsigned short ushort_t;
typedef short short8 __attribute__((ext_vector_type(8)));
typedef float f32x4 __attribute__((ext_vector_type(4)));
typedef unsigned uintx4 __attribute__((ext_vector_type(4)));

__device__ inline ushort_t f2bf(float f) {
    union { float f; unsigned u; } v; v.f = f;
    unsigned r = (v.u + 0x7FFFu + ((v.u >> 16) & 1u)) >> 16;
    return (ushort_t)r;
}
__device__ inline float bf_lo(unsigned u) {
    union { unsigned u; float f; } v; v.u = u << 16;
    return v.f;
}
__device__ inline float bf_hi(unsigned u) {
    union { unsigned u; float f; } v; v.u = u & 0xffff0000u;
    return v.f;
}

// ---------------------------------------------------------------------------
// Fused prep: xb (x fp32 -> bf16), Bt (W transposed bf16), and one zero row
// appended at xb[N_NODES] (gather padding target), one launch.
// ---------------------------------------------------------------------------
__global__ __launch_bounds__(256) void prep_kernel(const float* __restrict__ x,
                                                   ushort_t* __restrict__ xb,
                                                   const float* __restrict__ W_rel,
                                                   const float* __restrict__ W_root,
                                                   ushort_t* __restrict__ Bt) {
    int b = blockIdx.x;
    if (b < XB_BLOCKS) {
        int i = b * 256 + threadIdx.x;            // float4 index
        float4 v = ((const float4*)x)[i];
        unsigned lo = (unsigned)f2bf(v.x) | ((unsigned)f2bf(v.y) << 16);
        unsigned hi = (unsigned)f2bf(v.z) | ((unsigned)f2bf(v.w) << 16);
        ((uint2*)xb)[i] = make_uint2(lo, hi);
    } else if (b < XB_BLOCKS + BT_BLOCKS) {
        int i = (b - XB_BLOCKS) * 256 + threadIdx.x;
        int r   = i >> 14;
        int rem = i & 16383;
        int n   = rem >> 7;
        int k   = rem & 127;
        const float* W = (r < NREL) ? (W_rel + (size_t)r * DIM * DIM) : W_root;
        Bt[i] = f2bf(W[(size_t)k * DIM + n]);
    } else {
        // zero row at node index N_NODES: 128 bf16 = 32 x uint2
        if (threadIdx.x < 32)
            ((uint2*)(xb + (size_t)N_NODES * DIM))[threadIdx.x] = make_uint2(0u, 0u);
    }
}

// ---------------------------------------------------------------------------
// Count edges per key AND record each edge's within-bucket rank, packed as
// (key << 13) | rank.
// ---------------------------------------------------------------------------
__global__ __launch_bounds__(256) void count_rank_kernel(const int* __restrict__ ei,
                                                         const int* __restrict__ et,
                                                         unsigned* __restrict__ cnt,
                                                         unsigned* __restrict__ krk) {
    int e = blockIdx.x * 256 + threadIdx.x;
    if (e < N_EDGES) {
        int dst = ei[N_EDGES + e];
        unsigned key = (unsigned)dst * NREL + (unsigned)et[e];
        unsigned rank = atomicAdd(&cnt[key], 1u);
        krk[e] = (key << 13) | rank;
    }
}

// ---------------------------------------------------------------------------
// Block-local exclusive scan: meta[key] = (local_excl_offset, cnt), plus
// per-block sums. Consumers add bsums[key>>10] for the global offset.
// ---------------------------------------------------------------------------
__global__ __launch_bounds__(256) void scan1_kernel(const unsigned* __restrict__ cnt,
                                                    uint2* __restrict__ meta,
                                                    unsigned* __restrict__ bsums) {
    __shared__ unsigned lds[256];
    int tid = threadIdx.x;
    int i0  = blockIdx.x * SCAN_CHUNK + tid * 4;
    unsigned v[4], incl[4];
    unsigned s = 0;
#pragma unroll
    for (int j = 0; j < 4; ++j) {
        v[j] = (i0 + j < NKEYS) ? cnt[i0 + j] : 0u;
        s += v[j];
        incl[j] = s;
    }
    lds[tid] = s;
    __syncthreads();
    for (int off = 1; off < 256; off <<= 1) {
        unsigned a = (tid >= off) ? lds[tid - off] : 0u;
        __syncthreads();
        lds[tid] += a;
        __syncthreads();
    }
    unsigned base = lds[tid] - s;
#pragma unroll
    for (int j = 0; j < 4; ++j) {
        if (i0 + j < NKEYS) meta[i0 + j] = make_uint2(base + incl[j] - v[j], v[j]);
    }
    if (tid == 255) bsums[blockIdx.x] = lds[255];
}

__global__ __launch_bounds__(512) void scan2_kernel(unsigned* __restrict__ bsums) {
    __shared__ unsigned lds[512];
    int tid = threadIdx.x;
    unsigned v = (tid < SCAN_NBLK) ? bsums[tid] : 0u;
    lds[tid] = v;
    __syncthreads();
    for (int off = 1; off < 512; off <<= 1) {
        unsigned a = (tid >= off) ? lds[tid - off] : 0u;
        __syncthreads();
        lds[tid] += a;
        __syncthreads();
    }
    if (tid < SCAN_NBLK) bsums[tid] = lds[tid] - v;
}

// ---------------------------------------------------------------------------
// Atomic-free counting-sort fill: p = meta[key].x + bsums[key>>10] + rank.
// ---------------------------------------------------------------------------
__global__ __launch_bounds__(256) void fill_kernel(const int* __restrict__ ei,
                                                   const unsigned* __restrict__ krk,
                                                   const uint2* __restrict__ meta,
                                                   const unsigned* __restrict__ bsums,
                                                   int* __restrict__ sorted_src) {
    int e = blockIdx.x * 256 + threadIdx.x;
    if (e < N_EDGES) {
        unsigned kr   = krk[e];
        unsigned key  = kr >> 13;
        unsigned rank = kr & 8191u;
        unsigned p = meta[key].x + bsums[key >> 10] + rank;
        sorted_src[p] = ei[e];
    }
}

// ---------------------------------------------------------------------------
// R13 (kept): each half-wave owns TWO adjacent buckets with independent
// accumulator sets -> 2 independent load chains in flight per half-wave.
// Zero-row padding (index N_NODES) -> tail-free fused inner loop.
// ---------------------------------------------------------------------------
__global__ __launch_bounds__(256) void aggregate_kernel(const uint2* __restrict__ meta,
                                                        const unsigned* __restrict__ bsums,
                                                        const int* __restrict__ sorted_src,
                                                        const ushort_t* __restrict__ xb,
                                                        ushort_t* __restrict__ h,
                                                        int r0, int cr) {
    int hw = threadIdx.x >> 5;                      // half-wave id 0..7
    int sl = threadIdx.x & 31;                      // lane covers 4 feats
    int g0 = blockIdx.x * 16 + hw * 2;              // first bucket
    int g1 = g0 + 1;
    int total = N_NODES * cr;
    if (g0 >= total) return;

    unsigned key0, key1;
    if (cr == NREL) {
        key0 = (unsigned)g0;
        key1 = (unsigned)g1;
    } else {
        int n0 = g0 / cr, rl0 = g0 - n0 * cr;
        key0 = (unsigned)n0 * NREL + (unsigned)(r0 + rl0);
        int n1 = g1 / cr, rl1 = g1 - n1 * cr;
        key1 = (unsigned)n1 * NREL + (unsigned)(r0 + rl1);
    }
    uint2 md0 = meta[key0];
    unsigned st0 = md0.x + bsums[key0 >> 10];
    unsigned mc0 = md0.y;
    unsigned st1 = 0u, mc1 = 0u;
    if (g1 < total) {
        uint2 md1 = meta[key1];
        st1 = md1.x + bsums[key1 >> 10];
        mc1 = md1.y;
    }

    float a00 = 0.f, a01 = 0.f, a02 = 0.f, a03 = 0.f;
    float a10 = 0.f, a11 = 0.f, a12 = 0.f, a13 = 0.f;
    const char* xbase = (const char*)xb;
    unsigned slb = (unsigned)sl << 3;               // byte offset within row

    unsigned c0 = 0, c1 = 0;
    while (c0 < mc0 || c1 < mc1) {
        // two independent coalesced index loads (OOR lanes -> zero row)
        int sv0 = (c0 + (unsigned)sl < mc0) ? sorted_src[st0 + c0 + sl] : N_NODES;
        int sv1 = (c1 + (unsigned)sl < mc1) ? sorted_src[st1 + c1 + sl] : N_NODES;
        unsigned rem0 = (c0 < mc0) ? ((mc0 - c0 > 32u) ? 32u : (mc0 - c0)) : 0u;
        unsigned rem1 = (c1 < mc1) ? ((mc1 - c1 > 32u) ? 32u : (mc1 - c1)) : 0u;
        unsigned rm = rem0 > rem1 ? rem0 : rem1;
        for (unsigned j = 0; j < rm; j += 4) {
            int s00 = __shfl(sv0, (int)j,     32);
            int s01 = __shfl(sv0, (int)j + 1, 32);
            int s02 = __shfl(sv0, (int)j + 2, 32);
            int s03 = __shfl(sv0, (int)j + 3, 32);
            int s10 = __shfl(sv1, (int)j,     32);
            int s11 = __shfl(sv1, (int)j + 1, 32);
            int s12 = __shfl(sv1, (int)j + 2, 32);
            int s13 = __shfl(sv1, (int)j + 3, 32);
            uint2 d00 = *(const uint2*)(xbase + ((((unsigned)s00) << 8) | slb));
            uint2 d01 = *(const uint2*)(xbase + ((((unsigned)s01) << 8) | slb));
            uint2 d02 = *(const uint2*)(xbase + ((((unsigned)s02) << 8) | slb));
            uint2 d03 = *(const uint2*)(xbase + ((((unsigned)s03) << 8) | slb));
            uint2 d10 = *(const uint2*)(xbase + ((((unsigned)s10) << 8) | slb));
            uint2 d11 = *(const uint2*)(xbase + ((((unsigned)s11) << 8) | slb));
            uint2 d12 = *(const uint2*)(xbase + ((((unsigned)s12) << 8) | slb));
            uint2 d13 = *(const uint2*)(xbase + ((((unsigned)s13) << 8) | slb));
            a00 += (bf_lo(d00.x) + bf_lo(d01.x)) + (bf_lo(d02.x) + bf_lo(d03.x));
            a01 += (bf_hi(d00.x) + bf_hi(d01.x)) + (bf_hi(d02.x) + bf_hi(d03.x));
            a02 += (bf_lo(d00.y) + bf_lo(d01.y)) + (bf_lo(d02.y) + bf_lo(d03.y));
            a03 += (bf_hi(d00.y) + bf_hi(d01.y)) + (bf_hi(d02.y) + bf_hi(d03.y));
            a10 += (bf_lo(d10.x) + bf_lo(d11.x)) + (bf_lo(d12.x) + bf_lo(d13.x));
            a11 += (bf_hi(d10.x) + bf_hi(d11.x)) + (bf_hi(d12.x) + bf_hi(d13.x));
            a12 += (bf_lo(d10.y) + bf_lo(d11.y)) + (bf_lo(d12.y) + bf_lo(d13.y));
            a13 += (bf_hi(d10.y) + bf_hi(d11.y)) + (bf_hi(d12.y) + bf_hi(d13.y));
        }
        c0 += rem0;
        c1 += rem1;
    }

    float inv0 = 1.0f / fmaxf((float)mc0, 1.0f);
    unsigned lo0 = (unsigned)f2bf(a00 * inv0) | ((unsigned)f2bf(a01 * inv0) << 16);
    unsigned hi0 = (unsigned)f2bf(a02 * inv0) | ((unsigned)f2bf(a03 * inv0) << 16);
    ((uint2*)(h + (size_t)g0 * DIM))[sl] = make_uint2(lo0, hi0);
    if (g1 < total) {
        float inv1 = 1.0f / fmaxf((float)mc1, 1.0f);
        unsigned lo1 = (unsigned)f2bf(a10 * inv1) | ((unsigned)f2bf(a11 * inv1) << 16);
        unsigned hi1 = (unsigned)f2bf(a12 * inv1) | ((unsigned)f2bf(a13 * inv1) << 16);
        ((uint2*)(h + (size_t)g1 * DIM))[sl] = make_uint2(lo1, hi1);
    }
}

// ---------------------------------------------------------------------------
// LDS-staged MFMA GEMM + optional fused bias+LN+ReLU.  [R1 known-good form:
// both A and B staged in LDS — R2's B-from-global put an L2 hit on the MFMA
// critical path (MfmaUtil 3.5%, 162 us) and the grid (391 blocks / 256 CU)
// caps occupancy regardless of LDS, so Bs staging costs nothing.]
// ---------------------------------------------------------------------------
__global__ __launch_bounds__(512) void gemm_ln_kernel(const ushort_t* __restrict__ h,
                                                      int cr, int r0,
                                                      const ushort_t* __restrict__ xb,
                                                      const ushort_t* __restrict__ Bt,
                                                      int include_root,
                                                      const float* __restrict__ bias,
                                                      const float* __restrict__ gamma,
                                                      const float* __restrict__ beta,
                                                      float* __restrict__ out,
                                                      int accumulate, int do_ln) {
    __shared__ __align__(16) ushort_t As[128 * A_STRIDE];   // 34.8 KB
    __shared__ __align__(16) ushort_t Bs[128 * B_STRIDE];   // 34.8 KB

    int tid  = threadIdx.x;
    int w    = tid >> 6;          // 0..7
    int lane = tid & 63;
    int m    = lane & 15;
    int quad = lane >> 4;
    int n0   = blockIdx.x * 128;

    f32x4 acc[8];
#pragma unroll
    for (int j = 0; j < 8; ++j) acc[j] = (f32x4){0.f, 0.f, 0.f, 0.f};

    int nrel = cr + include_root;
    for (int rr = 0; rr < nrel; ++rr) {
        int rel = (rr < cr) ? (r0 + rr) : NREL;

        // ---- stage B: 2048 x 16B chunks, 4 per thread (batched) ----
#pragma unroll
        for (int p = 0; p < 4; ++p) {
            int c = tid + 512 * p;
            int row = c >> 4, ch = c & 15;
            uintx4 v = *(const uintx4*)(Bt + ((size_t)rel * DIM + row) * DIM + ch * 8);
            *(uintx4*)&Bs[row * B_STRIDE + ch * 8] = v;
        }
        // ---- stage A: 2048 x 16B chunks (128 rows), 4 per thread ----
#pragma unroll
        for (int p = 0; p < 4; ++p) {
            int c = tid + 512 * p;
            int row = c >> 4, ch = c & 15;
            uintx4 v = (uintx4){0u, 0u, 0u, 0u};
            int node = n0 + row;
            if (node < N_NODES) {
                const ushort_t* src = (rr < cr)
                    ? (h + ((size_t)node * cr + rr) * DIM)
                    : (xb + (size_t)node * DIM);
                v = *(const uintx4*)(src + ch * 8);
            }
            *(uintx4*)&As[row * A_STRIDE + ch * 8] = v;
        }
        __syncthreads();

        // ---- 32 MFMA per wave ----
#pragma unroll
        for (int t = 0; t < 4; ++t) {
            short8 af = *(const short8*)&As[(w * 16 + m) * A_STRIDE + t * 32 + quad * 8];
#pragma unroll
            for (int j = 0; j < 8; ++j) {
                short8 bf = *(const short8*)&Bs[(j * 16 + m) * B_STRIDE + t * 32 + quad * 8];
                acc[j] = __builtin_amdgcn_mfma_f32_16x16x32_bf16(af, bf, acc[j], 0, 0, 0);
            }
        }
        __syncthreads();
    }

    // ---- epilogue ----
    if (do_ln) {
        float bj[8], gj[8], btj[8];
#pragma unroll
        for (int j = 0; j < 8; ++j) {
            bj[j]  = bias[j * 16 + m];
            gj[j]  = gamma[j * 16 + m];
            btj[j] = beta[j * 16 + m];
        }
#pragma unroll
        for (int i = 0; i < 4; ++i) {
            float s = 0.f, sq = 0.f;
#pragma unroll
            for (int j = 0; j < 8; ++j) {
                float v = acc[j][i] + bj[j];
                s  += v;
                sq += v * v;
            }
#pragma unroll
            for (int off = 1; off < 16; off <<= 1) {
                s  += __shfl_xor(s, off, 64);
                sq += __shfl_xor(sq, off, 64);
            }
            float mean = s * (1.0f / DIM);
            float var  = sq * (1.0f / DIM) - mean * mean;
            float rstd = rsqrtf(var + LN_EPS);
            int node = n0 + w * 16 + quad * 4 + i;
            if (node < N_NODES) {
#pragma unroll
                for (int j = 0; j < 8; ++j) {
                    float v = acc[j][i] + bj[j];
                    v = (v - mean) * rstd * gj[j] + btj[j];
                    out[(size_t)node * DIM + j * 16 + m] = fmaxf(v, 0.f);
                }
            }
        }
    } else {
#pragma unroll
        for (int i = 0; i < 4; ++i) {
            int node = n0 + w * 16 + quad * 4 + i;
            if (node < N_NODES) {
#pragma unroll
                for (int j = 0; j < 8; ++j) {
                    size_t o = (size_t)node * DIM + j * 16 + m;
                    float v = acc[j][i];
                    if (accumulate) v += out[o];
                    out[o] = v;
                }
            }
        }
    }
}

// ---------------------------------------------------------------------------
// Standalone bias + LayerNorm + ReLU (fallback for chunked path).
// ---------------------------------------------------------------------------
__global__ __launch_bounds__(256) void ln_kernel(float* __restrict__ out,
                                                 const float* __restrict__ bias,
                                                 const float* __restrict__ gamma,
                                                 const float* __restrict__ beta) {
    int row  = blockIdx.x * 4 + (threadIdx.x >> 6);
    int lane = threadIdx.x & 63;
    if (row >= N_NODES) return;
    float2 v = *(float2*)(out + (size_t)row * DIM + lane * 2);
    float2 bi = *(const float2*)(bias + lane * 2);
    v.x += bi.x;
    v.y += bi.y;
    float s  = v.x + v.y;
    float sq = v.x * v.x + v.y * v.y;
#pragma unroll
    for (int off = 32; off > 0; off >>= 1) {
        s  += __shfl_xor(s, off, 64);
        sq += __shfl_xor(sq, off, 64);
    }
    float mean = s * (1.0f / DIM);
    float var  = sq * (1.0f / DIM) - mean * mean;
    float rstd = rsqrtf(var + LN_EPS);
    float2 g = *(const float2*)(gamma + lane * 2);
    float2 b = *(const float2*)(beta + lane * 2);
    v.x = fmaxf((v.x - mean) * rstd * g.x + b.x, 0.f);
    v.y = fmaxf((v.y - mean) * rstd * g.y + b.y, 0.f);
    *(float2*)(out + (size_t)row * DIM + lane * 2) = v;
}

// ---------------------------------------------------------------------------
extern "C" void kernel_launch(void* const* d_in, const int* in_sizes, int n_in,
                              void* d_out, int out_size, void* d_ws, size_t ws_size,
                              hipStream_t stream) {
    const float* x      = (const float*)d_in[0];
    const int*   ei     = (const int*)d_in[1];
    const int*   et     = (const int*)d_in[2];
    const float* W_rel  = (const float*)d_in[4];
    const float* W_root = (const float*)d_in[5];
    const float* bias   = (const float*)d_in[6];
    const float* gamma  = (const float*)d_in[7];
    const float* beta   = (const float*)d_in[8];
    float*       out    = (float*)d_out;

    // ---- workspace layout ----
    char* ws = (char*)d_ws;
    size_t off = 0;
    auto alloc = [&](size_t bytes) { char* p = ws + off; off = (off + bytes + 255) & ~(size_t)255; return p; };
    unsigned* cnt        = (unsigned*)alloc((size_t)NKEYS * 4);
    uint2*    meta       = (uint2*)alloc((size_t)NKEYS * 8);
    unsigned* bsums      = (unsigned*)alloc((size_t)SCAN_NBLK * 4);
    unsigned* krk        = (unsigned*)alloc((size_t)N_EDGES * 4);
    int*      sorted_src = (int*)alloc((size_t)N_EDGES * 4);
    ushort_t* Bt         = (ushort_t*)alloc((size_t)9 * DIM * DIM * 2);
    ushort_t* xb         = (ushort_t*)alloc((size_t)(N_NODES + 1) * DIM * 2);  // +1 zero row
    size_t fixedOff = off;
    ushort_t* h = (ushort_t*)(ws + fixedOff);
    size_t availB = ws_size > fixedOff ? ws_size - fixedOff : 0;
    size_t perRel = (size_t)N_NODES * DIM * 2;   // 12.8 MB per relation (bf16)
    int chunkR = (int)(availB / perRel);
    if (chunkR > NREL) chunkR = NREL;
    if (chunkR < 1)    chunkR = 1;

    // ---- build counting sort (rank recorded during count; no fill atomic) ----
    hipMemsetAsync(cnt, 0, (size_t)NKEYS * 4, stream);
    prep_kernel<<<XB_BLOCKS + BT_BLOCKS + 1, 256, 0, stream>>>(x, xb, W_rel, W_root, Bt);
    count_rank_kernel<<<(N_EDGES + 255) / 256, 256, 0, stream>>>(ei, et, cnt, krk);
    scan1_kernel<<<SCAN_NBLK, 256, 0, stream>>>(cnt, meta, bsums);
    scan2_kernel<<<1, 512, 0, stream>>>(bsums);
    fill_kernel<<<(N_EDGES + 255) / 256, 256, 0, stream>>>(ei, krk, meta, bsums, sorted_src);

    int gemmGrid = (N_NODES + 127) / 128;   // 391 blocks

    if (chunkR >= NREL) {
        int nbuck = N_NODES * NREL;
        aggregate_kernel<<<(nbuck + 15) / 16, 256, 0, stream>>>(meta, bsums, sorted_src,
                                                                xb, h, 0, NREL);
        gemm_ln_kernel<<<gemmGrid, 512, 0, stream>>>(h, NREL, 0, xb, Bt, 1,
                                                     bias, gamma, beta, out, 0, 1);
    } else {
        for (int r0 = 0; r0 < NREL; r0 += chunkR) {
            int cr = (NREL - r0 < chunkR) ? (NREL - r0) : chunkR;
            int nbuck = N_NODES * cr;
            aggregate_kernel<<<(nbuck + 15) / 16, 256, 0, stream>>>(meta, bsums, sorted_src,
                                                                    xb, h, r0, cr);
            int include_root = (r0 + cr == NREL) ? 1 : 0;
            gemm_ln_kernel<<<gemmGrid, 512, 0, stream>>>(h, cr, r0, xb, Bt, include_root,
                                                         bias, gamma, beta, out,
                                                         r0 > 0 ? 1 : 0, 0);
        }
        ln_kernel<<<(N_NODES + 3) / 4, 256, 0, stream>>>(out, bias, gamma, beta);
    }
}